// Round 2
// baseline (105.984 us; speedup 1.0000x reference)
//
#include <hip/hip_runtime.h>

#define D_ATOM 128
#define D_PAIR 64
#define D_HID  32
#define NLOC   384

// ws layout: ab[384*64] f32 at byte 0 (96 KB); T[384*32*64] f32 at byte 98304 (3 MB).

// ab[n][h] = (sum_d m[n,d] * W_in[h,d] + b_in[h]) * op_mask
__global__ __launch_bounds__(256) void k_ab(const float* __restrict__ m,
                                            const float* __restrict__ W_in,
                                            const float* __restrict__ b_in,
                                            const float* __restrict__ op_mask,
                                            float* __restrict__ ab) {
    const int t  = threadIdx.x;
    const int h  = t & 63;
    const int ng = __builtin_amdgcn_readfirstlane(t >> 6);
    const int n  = blockIdx.x * 4 + ng;
    const float* mrow = m + n * D_ATOM;      // wave-uniform address
    const float* wrow = W_in + h * D_ATOM;
    float acc = 0.f;
#pragma unroll
    for (int dq = 0; dq < D_ATOM / 4; ++dq) {
        const float4 w  = *reinterpret_cast<const float4*>(wrow + dq * 4);
        const float4 mv = *reinterpret_cast<const float4*>(mrow + dq * 4);
        acc += w.x * mv.x + w.y * mv.y + w.z * mv.z + w.w * mv.w;
    }
    ab[n * 64 + h] = (acc + b_in[h]) * op_mask[0];
}

// T[j][x][p] = sum_y b[j][y] * W_out[p][x*32+y],  b[j][y] = ab[j*64 + 32 + y]
__global__ __launch_bounds__(256) void k_T(const float* __restrict__ ab,
                                           const float* __restrict__ W_out,
                                           float* __restrict__ T) {
    const int t  = threadIdx.x;
    const int p  = t & 63;
    const int xl = t >> 6;                   // 0..3
    const int xt = blockIdx.x & 7;           // 0..7
    const int jt = blockIdx.x >> 3;          // 0..23
    const int x  = xt * 4 + xl;              // 0..31
    float4 w[8];
#pragma unroll
    for (int yq = 0; yq < 8; ++yq)
        w[yq] = *reinterpret_cast<const float4*>(W_out + p * 1024 + x * 32 + yq * 4);
#pragma unroll
    for (int jj = 0; jj < 16; ++jj) {
        const int j = jt * 16 + jj;
        const float* brow = ab + j * 64 + 32;   // wave-uniform address
        float acc = 0.f;
#pragma unroll
        for (int yq = 0; yq < 8; ++yq) {
            const float4 b4 = *reinterpret_cast<const float4*>(brow + yq * 4);
            acc += b4.x * w[yq].x + b4.y * w[yq].y + b4.z * w[yq].z + b4.w * w[yq].w;
        }
        T[j * 2048 + x * 64 + p] = acc;          // lanes p consecutive: coalesced
    }
}

// out[i][j][p] = (sum_x a[i][x] * T[j][x][p] + b_out[p]) * op_norm
__global__ __launch_bounds__(256) void k_main(const float* __restrict__ ab,
                                              const float* __restrict__ T,
                                              const float* __restrict__ b_out,
                                              const float* __restrict__ op_norm,
                                              float* __restrict__ out) {
    const int t    = threadIdx.x;
    const int p    = t & 63;
    const int wv   = __builtin_amdgcn_readfirstlane(t >> 6);  // 0..3, wave-uniform
    const int j    = blockIdx.x >> 1;
    const int half = blockIdx.x & 1;

    float treg[32];
#pragma unroll
    for (int x = 0; x < 32; ++x) treg[x] = T[j * 2048 + x * 64 + p];  // coalesced
    const float bout = b_out[p];
    const float norm = op_norm[0];

    const int ibase = half * 192 + wv * 48;    // this wave's 48 i's
    for (int c = 0; c < 6; ++c) {
        const int i0 = ibase + c * 8;
        float acc[8];
#pragma unroll
        for (int r = 0; r < 8; ++r) acc[r] = bout;
        const float* arow = ab + i0 * 64;      // wave-uniform addresses below
#pragma unroll
        for (int xq = 0; xq < 8; ++xq) {
#pragma unroll
            for (int r = 0; r < 8; ++r) {
                const float4 av = *reinterpret_cast<const float4*>(arow + r * 64 + xq * 4);
                acc[r] += av.x * treg[xq * 4 + 0] + av.y * treg[xq * 4 + 1] +
                          av.z * treg[xq * 4 + 2] + av.w * treg[xq * 4 + 3];
            }
        }
        float* orow = out + (i0 * NLOC + j) * 64 + p;
#pragma unroll
        for (int r = 0; r < 8; ++r)
            orow[r * NLOC * 64] = acc[r] * norm;   // 256 B/wave coalesced
    }
}

extern "C" void kernel_launch(void* const* d_in, const int* in_sizes, int n_in,
                              void* d_out, int out_size, void* d_ws, size_t ws_size,
                              hipStream_t stream) {
    const float* m       = (const float*)d_in[0];
    // d_in[1] = nlist (unused by the reference computation)
    const float* op_mask = (const float*)d_in[2];
    const float* op_norm = (const float*)d_in[3];
    const float* W_in    = (const float*)d_in[4];
    const float* b_in    = (const float*)d_in[5];
    const float* W_out   = (const float*)d_in[6];
    const float* b_out   = (const float*)d_in[7];
    float* out = (float*)d_out;

    float* ab = (float*)d_ws;                          // 384*64 f32
    float* T  = (float*)((char*)d_ws + 98304);         // 384*32*64 f32

    k_ab  <<<96,  256, 0, stream>>>(m, W_in, b_in, op_mask, ab);
    k_T   <<<192, 256, 0, stream>>>(ab, W_out, T);
    k_main<<<768, 256, 0, stream>>>(ab, T, b_out, op_norm, out);
}